// Round 14
// baseline (56.097 us; speedup 1.0000x reference)
//
#include <hip/hip_runtime.h>

typedef _Float16 f16;
typedef __attribute__((ext_vector_type(2))) __fp16 fp16x2;
typedef __attribute__((ext_vector_type(8))) _Float16 f16x8;
typedef __attribute__((ext_vector_type(16))) float f32x16;
typedef __attribute__((ext_vector_type(4))) unsigned int u32x4;

#define NPTS (16 * 32768)
// packed-weight frag layout (32x32x16 fragments, 1KB each = 64 lanes x 16B)
#define W0F 0                  // 16 frags (4 mt x 4 kt)   16KB
#define W1F (16 * 1024)        // 32 frags (4 mt x 8 kt)   32KB
#define W2F (48 * 1024)        // 32 frags                 32KB
#define WOF (80 * 1024)        // 8 frags (8 kt)           8KB
#define FRAGS_BYTES (88 * 1024)
#define TENC_OFF FRAGS_BYTES   // ws: 16 batches x 16 f32
#define WS_NEEDED (FRAGS_BYTES + 1024)
// LDS: weights mirror [0,88K) + 8 waves x 4KB transpose scratch = 120KB
#define SCR_OFF FRAGS_BYTES
#define LDS_TOTAL (SCR_OFF + 8 * 4096)

// k-position maps within a 16-wide kt block (h = lane>>5, j = elem 0..7):
//   natural (layer0, matches feature build):  k = 8h + j
//   chained (layers 1,2,out, from D layout):  k = (j&3) + 8*(j>>2) + 4h
// D(32x32) layout: col = lane&31, row = (r&3) + 8*(r>>2) + 4*(lane>>5), r=0..15.
// Chain proof: Bout frag kt'=2mt+f elem j := D reg r=8f+j -> row = 16f + kperm(h,j)
//   -> global k = 32mt + 16f + kperm = 16*kt' + kperm. A of next layer packed same way.
__global__ void pack_weights(const float* __restrict__ time, const float* __restrict__ te0,
                             const float* __restrict__ te1, const float* __restrict__ W0,
                             const float* __restrict__ W1, const float* __restrict__ W2,
                             const float* __restrict__ Wout, unsigned char* __restrict__ ws) {
  const int bi = blockIdx.x;
  const int l = threadIdx.x;
  const int h = l >> 5, r32 = l & 31;
  if (bi < 88) {
    const float* W; int obase, mt, kt, kmax; bool natural, outcol;
    if (bi < 16)      { W = W0;   mt = bi >> 2;        kt = bi & 3;  obase = W0F; kmax = 55;  natural = true;  outcol = false; }
    else if (bi < 48) { W = W1;   mt = (bi - 16) >> 3; kt = (bi - 16) & 7; obase = W1F; kmax = 128; natural = false; outcol = false; }
    else if (bi < 80) { W = W2;   mt = (bi - 48) >> 3; kt = (bi - 48) & 7; obase = W2F; kmax = 128; natural = false; outcol = false; }
    else              { W = Wout; mt = 0;              kt = bi - 80; obase = WOF; kmax = 128; natural = false; outcol = true;  }
    const int m = mt * 32 + r32;
    const int fi = outcol ? kt : (bi < 16 ? mt * 4 + kt : mt * 8 + kt);
    f16 vals[8] __attribute__((aligned(16)));
#pragma unroll
    for (int j = 0; j < 8; ++j) {
      const int kl = natural ? (8 * h + j) : ((j & 3) + 8 * (j >> 2) + 4 * h);
      const int k = kt * 16 + kl;
      float v = 0.f;
      if (k < kmax) v = outcol ? ((r32 == 0) ? Wout[k] : 0.f) : W[k * 128 + m];
      vals[j] = (f16)v;
    }
    *(u32x4*)(ws + obase + (fi * 64 + l) * 16) = *(const u32x4*)vals;
  } else {
    // time encoding: 16 batches x 16 dims fp32
    const int idx = (bi - 88) * 64 + l;  // 0..255
    const int b = idx >> 4, d = idx & 15;
    const float t = time[b];
    const float* emb; int L, dd;
    if (d < 8) { emb = te0; L = 5;  dd = d; }
    else       { emb = te1; L = 20; dd = d - 8; }
    const float tL = t * (float)L;
    int i = (int)floorf(tL);
    i = i < 0 ? 0 : (i > L - 1 ? L - 1 : i);
    const float wlo = (float)(i + 1) - tL;
    float v = wlo * emb[i * 8 + dd] + (1.f - wlo) * emb[(i + 1) * 8 + dd];
    if (t >= 1.f) v = emb[L * 8 + dd];
    ((float*)(ws + TENC_OFF))[idx] = v;
  }
}

// ---------------- one layer, 32x32x16: D = W_sw(128xK) * B(Kx64), weights from LDS ----------------
// Per mt strip: bias as C-init (rows 32mt + (r&3)+8(r>>2)+4h), 2*KT MFMAs (one A-frag
// ds_read feeds both nt tiles), relu+pkrtz epilogue packs D regs straight into the
// next layer's B fragments (k-perm chain, register-local).
template <int KT>
__device__ __forceinline__ void layer32(const char* __restrict__ wlds,
                                        const float* __restrict__ bias,
                                        const f16x8 (&Bin)[2][KT], f16x8 (&Bout)[2][8],
                                        int lane) {
  const int h = lane >> 5;
#pragma unroll
  for (int mt = 0; mt < 4; ++mt) {
    f32x16 c;
#pragma unroll
    for (int q = 0; q < 4; ++q) {
      const float4 b4 = *(const float4*)(bias + mt * 32 + q * 8 + 4 * h);
      c[4 * q] = b4.x; c[4 * q + 1] = b4.y; c[4 * q + 2] = b4.z; c[4 * q + 3] = b4.w;
    }
    f32x16 a0 = c, a1 = c;
    __builtin_amdgcn_s_setprio(1);
#pragma unroll
    for (int kt = 0; kt < KT; ++kt) {
      const f16x8 A = *(const f16x8*)(wlds + ((mt * KT + kt) * 64 + lane) * 16);
      a0 = __builtin_amdgcn_mfma_f32_32x32x16_f16(A, Bin[0][kt], a0, 0, 0, 0);
      a1 = __builtin_amdgcn_mfma_f32_32x32x16_f16(A, Bin[1][kt], a1, 0, 0, 0);
    }
    __builtin_amdgcn_s_setprio(0);
#pragma unroll
    for (int f = 0; f < 2; ++f) {
      union { fp16x2 h2[4]; f16x8 v; } u0, u1;
#pragma unroll
      for (int pq = 0; pq < 4; ++pq) {
        u0.h2[pq] = __builtin_amdgcn_cvt_pkrtz(fmaxf(a0[8 * f + 2 * pq], 0.f),
                                               fmaxf(a0[8 * f + 2 * pq + 1], 0.f));
        u1.h2[pq] = __builtin_amdgcn_cvt_pkrtz(fmaxf(a1[8 * f + 2 * pq], 0.f),
                                               fmaxf(a1[8 * f + 2 * pq + 1], 0.f));
      }
      Bout[0][2 * mt + f] = u0.v;
      Bout[1][2 * mt + f] = u1.v;
    }
  }
}

// ---------------- fused main kernel: 512 thr, weights in LDS, 32x32 MFMA ----------------
__global__ void __launch_bounds__(512, 1)
mlp_main(const float* __restrict__ xyz, const float* __restrict__ b0,
         const float* __restrict__ b1, const float* __restrict__ b2,
         const float* __restrict__ bout, const unsigned char* __restrict__ ws,
         float* __restrict__ out) {
  extern __shared__ char lds[];
  const int tid = threadIdx.x;
  const int lane = tid & 63, wv = tid >> 6;
  const int h = lane >> 5, r32 = lane & 31;

  // stage packed weights global -> LDS once per block (88KB, 11 iters)
  for (int i = tid; i < FRAGS_BYTES / 16; i += 512)
    *(u32x4*)(lds + i * 16) = *(const u32x4*)(ws + i * 16);
  __syncthreads();

  char* scr = lds + SCR_OFF + wv * 4096;  // per-wave transpose scratch (32 rows x 128B)
  const float bo = bout[0];

  const int pbase = blockIdx.x * 512 + wv * 64;
  const int p = pbase + lane;

  // ---- 64-dim feature row in f32, then pack pairs with cvt_pkrtz ----
  float ff[64];
  const float* tb = (const float*)(ws + TENC_OFF) + (blockIdx.x >> 6) * 16;  // batch = p/32768
#pragma unroll
  for (int i = 0; i < 16; ++i) ff[i] = tb[i];
  const float xs0 = xyz[p * 3], xs1 = xyz[p * 3 + 1], xs2 = xyz[p * 3 + 2];
  const float pcs[3] = {(xs0 + 1.f) * 0.5f, (xs1 + 1.f) * 0.5f, (xs2 + 1.f) * 0.5f};
#pragma unroll
  for (int c = 0; c < 3; ++c) {
    ff[16 + c] = pcs[c];
    float s = __sinf(pcs[c]), co = __cosf(pcs[c]);
#pragma unroll
    for (int f = 0; f < 6; ++f) {
      ff[19 + f * 3 + c] = s;
      ff[37 + f * 3 + c] = co;
      const float s2 = 2.f * s * co, c2 = 1.f - 2.f * s * s;
      s = s2; co = c2;
    }
  }
#pragma unroll
  for (int i = 55; i < 64; ++i) ff[i] = 0.f;
  unsigned int fw[32];
#pragma unroll
  for (int i = 0; i < 32; ++i) {
    union { fp16x2 hh; unsigned int u; } cv;
    cv.hh = __builtin_amdgcn_cvt_pkrtz(ff[2 * i], ff[2 * i + 1]);
    fw[i] = cv.u;
  }

  // ---- transpose via per-wave scratch, two 32-point halves -> B0 fragments ----
  // B0[nh][kt] elem (h,j) = feat[32nh + r32][16kt + 8h + j]  (natural k-map)
  f16x8 B0[2][4];
#pragma unroll
  for (int nh = 0; nh < 2; ++nh) {
    if (h == nh) {
#pragma unroll
      for (int s = 0; s < 8; ++s)
        *(u32x4*)(scr + r32 * 128 + ((s ^ (r32 & 7)) * 16)) = ((const u32x4*)fw)[s];
    }
    asm volatile("s_waitcnt lgkmcnt(0)" ::: "memory");
#pragma unroll
    for (int kt = 0; kt < 4; ++kt)
      B0[nh][kt] = *(const f16x8*)(scr + r32 * 128 + (((2 * kt + h) ^ (r32 & 7)) * 16));
    asm volatile("s_waitcnt lgkmcnt(0)" ::: "memory");
  }

  // ---- 3 hidden layers, register-chained, weights from LDS ----
  f16x8 Bx[2][8], By[2][8];
  layer32<4>((const char*)lds + W0F, b0, B0, Bx, lane);
  layer32<8>((const char*)lds + W1F, b1, Bx, By, lane);
  layer32<8>((const char*)lds + W2F, b2, By, Bx, lane);

  // ---- output layer: M=32 padded (row 0 real), 16 MFMAs ----
  f32x16 o0, o1;
#pragma unroll
  for (int r = 0; r < 16; ++r) { o0[r] = bo; o1[r] = bo; }
  __builtin_amdgcn_s_setprio(1);
#pragma unroll
  for (int kt = 0; kt < 8; ++kt) {
    const f16x8 A = *(const f16x8*)((const char*)lds + WOF + (kt * 64 + lane) * 16);
    o0 = __builtin_amdgcn_mfma_f32_32x32x16_f16(A, Bx[0][kt], o0, 0, 0, 0);
    o1 = __builtin_amdgcn_mfma_f32_32x32x16_f16(A, Bx[1][kt], o1, 0, 0, 0);
  }
  __builtin_amdgcn_s_setprio(0);

  // row 0 lives in reg 0 of lanes 0..31 (h=0): two 128B half-wave stores
  if (lane < 32) {
    out[pbase + lane] = o0[0];
    out[pbase + 32 + lane] = o1[0];
  }
}

extern "C" void kernel_launch(void* const* d_in, const int* in_sizes, int n_in,
                              void* d_out, int out_size, void* d_ws, size_t ws_size,
                              hipStream_t stream) {
  const float* time = (const float*)d_in[0];
  const float* xyz  = (const float*)d_in[1];
  const float* te0  = (const float*)d_in[2];
  const float* te1  = (const float*)d_in[3];
  const float* W0   = (const float*)d_in[4];
  const float* b0   = (const float*)d_in[5];
  const float* W1   = (const float*)d_in[6];
  const float* b1   = (const float*)d_in[7];
  const float* W2   = (const float*)d_in[8];
  const float* b2   = (const float*)d_in[9];
  const float* Wout = (const float*)d_in[10];
  const float* bout = (const float*)d_in[11];
  float* out = (float*)d_out;
  unsigned char* ws = (unsigned char*)d_ws;
  if (ws_size < WS_NEEDED) return;

  hipFuncSetAttribute((const void*)mlp_main,
                      hipFuncAttributeMaxDynamicSharedMemorySize, LDS_TOTAL);

  pack_weights<<<92, 64, 0, stream>>>(time, te0, te1, W0, W1, W2, Wout, ws);
  mlp_main<<<NPTS / 512, 512, LDS_TOTAL, stream>>>(xyz, b0, b1, b2, bout, ws, out);
}